// Round 1
// baseline (70.027 us; speedup 1.0000x reference)
//
#include <hip/hip_runtime.h>

// Problem constants (from reference): B=64, H=W=512, K=7, VALID conv -> 506x506 out.
#define HW       512
#define OW       506
#define KS       7
#define TILE_OUT 64   // output tile per block (64x64)
#define TILE_IN  70   // input halo tile (64 + 6)
#define LDS_STR  72   // padded LDS row stride (floats)

__global__ __launch_bounds__(256) void conv7x7_kernel(
    const float* __restrict__ in,      // [B][512][512]
    const float* __restrict__ weight,  // [7][7]
    const float* __restrict__ bias,    // [1]
    float* __restrict__ out)           // [B][506][506]
{
    __shared__ float tile[TILE_IN][LDS_STR];

    const int tid = threadIdx.x;
    const int x0  = blockIdx.x * TILE_OUT;
    const int y0  = blockIdx.y * TILE_OUT;
    const int b   = blockIdx.z;

    const float* __restrict__ inb = in + (size_t)b * HW * HW;

    // ---- weights + bias into SGPRs (uniform across lanes) ----
    float wv[KS * KS];
#pragma unroll
    for (int i = 0; i < KS * KS; ++i)
        wv[i] = __uint_as_float(__builtin_amdgcn_readfirstlane(__float_as_uint(weight[i])));
    const float bv = __uint_as_float(__builtin_amdgcn_readfirstlane(__float_as_uint(bias[0])));

    // ---- stage 70x70 input tile into LDS (coalesced float2 loads) ----
    // 70*70/2 = 2450 float2 elements; 35 pairs per row.
    for (int p = tid; p < (TILE_IN * TILE_IN / 2); p += 256) {
        const int r  = p / 35;
        const int c  = 2 * (p - r * 35);
        const int gy = y0 + r;
        const int gx = x0 + c;
        float2 v = make_float2(0.f, 0.f);
        // gx is even; gx<512 implies gx<=510 so gx+1<=511 is also in bounds.
        if (gy < HW && gx < HW)
            v = *reinterpret_cast<const float2*>(inb + gy * HW + gx);
        *reinterpret_cast<float2*>(&tile[r][c]) = v;
    }
    __syncthreads();

    // ---- each thread: 4x4 output register tile ----
    const int tx = tid & 15;
    const int ty = tid >> 4;
    const int cx = 4 * tx;  // tile-local col of first output
    const int cy = 4 * ty;  // tile-local row of first output

    float acc[4][4];
#pragma unroll
    for (int i = 0; i < 4; ++i)
#pragma unroll
        for (int j = 0; j < 4; ++j) acc[i][j] = 0.f;

#pragma unroll
    for (int rr = 0; rr < 10; ++rr) {
        // window of 10 input floats for this LDS row (16B-aligned vector reads)
        const float4 a4 = *reinterpret_cast<const float4*>(&tile[cy + rr][cx]);
        const float4 b4 = *reinterpret_cast<const float4*>(&tile[cy + rr][cx + 4]);
        const float2 c2 = *reinterpret_cast<const float2*>(&tile[cy + rr][cx + 8]);
        float win[10];
        win[0] = a4.x; win[1] = a4.y; win[2] = a4.z; win[3] = a4.w;
        win[4] = b4.x; win[5] = b4.y; win[6] = b4.z; win[7] = b4.w;
        win[8] = c2.x; win[9] = c2.y;

#pragma unroll
        for (int i = 0; i < 4; ++i) {
            const int kr = rr - i;            // compile-time after unroll
            if (kr >= 0 && kr < KS) {
#pragma unroll
                for (int kc = 0; kc < KS; ++kc) {
                    const float wk = wv[kr * KS + kc];
#pragma unroll
                    for (int j = 0; j < 4; ++j)
                        acc[i][j] = fmaf(wk, win[kc + j], acc[i][j]);
                }
            }
        }
    }

    // ---- store 4x4 outputs (+bias), float2 pairs, edge-guarded ----
    float* __restrict__ outb = out + (size_t)b * OW * OW;
#pragma unroll
    for (int i = 0; i < 4; ++i) {
        const int oy = y0 + cy + i;
        if (oy >= OW) continue;
        const int ox = x0 + cx;
        float* row = outb + (size_t)oy * OW + ox;
        if (ox + 3 < OW) {
            *reinterpret_cast<float2*>(row)     = make_float2(acc[i][0] + bv, acc[i][1] + bv);
            *reinterpret_cast<float2*>(row + 2) = make_float2(acc[i][2] + bv, acc[i][3] + bv);
        } else {
#pragma unroll
            for (int j = 0; j < 4; ++j)
                if (ox + j < OW) row[j] = acc[i][j] + bv;
        }
    }
}

extern "C" void kernel_launch(void* const* d_in, const int* in_sizes, int n_in,
                              void* d_out, int out_size, void* d_ws, size_t ws_size,
                              hipStream_t stream) {
    const float* enc_x  = (const float*)d_in[0];
    const float* weight = (const float*)d_in[1];
    const float* bias   = (const float*)d_in[2];
    float* out          = (float*)d_out;

    // ceil(506/64) = 8 tiles in x and y; 64 batches in z.
    dim3 grid(8, 8, 64);
    dim3 block(256);
    hipLaunchKernelGGL(conv7x7_kernel, grid, block, 0, stream,
                       enc_x, weight, bias, out);
}